// Round 1
// baseline (7861.809 us; speedup 1.0000x reference)
//
#include <hip/hip_runtime.h>

#define B_  128
#define S_  1024
#define H_  256
#define NM_ 16

typedef short bf16x8 __attribute__((ext_vector_type(8)));
typedef float f32x4  __attribute__((ext_vector_type(4)));

__device__ __forceinline__ short f2bf(float f) {
    unsigned u = __builtin_bit_cast(unsigned, f);
    unsigned r = (u + 0x7FFFu + ((u >> 16) & 1u)) >> 16;   // RNE
    return (short)r;
}
__device__ __forceinline__ bf16x8 zero8() {
    bf16x8 v;
    #pragma unroll
    for (int j = 0; j < 8; ++j) v[j] = 0;
    return v;
}
__device__ __forceinline__ float sigf(float x)  { return 1.0f / (1.0f + __expf(-x)); }
__device__ __forceinline__ float tanh_(float x) { return 1.0f - 2.0f / (1.0f + __expf(2.0f * x)); }

// Fused 2-layer LSTM. Blocks 0..63: g = bx&7 (batch group, XCD-coloc), role = bx>>3.
// role 0..3  -> layer0, gate-chunk q=role      (K = 256 h0 + 16 x, 9 k-tiles)
// role 4..7  -> layer1, gate-chunk q=role-4    (K = 256 h2 + 256 h1, 16 k-tiles)
// Each wave owns i,f,g,o n-tiles of one 16-hu slice -> c-state & gates stay in C/D frag layout.
__global__ __launch_bounds__(256, 1) void lstm_kernel(
    const float* __restrict__ x,
    const float* __restrict__ Wih0, const float* __restrict__ Whh0,
    const float* __restrict__ bih0, const float* __restrict__ bhh0,
    const float* __restrict__ Wih1, const float* __restrict__ Whh1,
    const float* __restrict__ bih1, const float* __restrict__ bhh1,
    short* __restrict__ h1, short* __restrict__ h2ring,
    float* __restrict__ hlast,
    int* __restrict__ flags0, int* __restrict__ flags1)
{
    const int g    = blockIdx.x & 7;
    const int role = blockIdx.x >> 3;
    const int lane = threadIdx.x & 63;
    const int wv   = threadIdx.x >> 6;
    const int n    = lane & 15;       // B-frag: gate col within tile; A-frag: batch row
    const int quad = lane >> 4;       // k-group / C-frag row group

    if (role < 4) {
        // ---------------- layer 0 ----------------
        const int q = role;
        const int hu_base = q * 64 + wv * 16;
        bf16x8 wf[4][9];
        float  bias[4];
        #pragma unroll
        for (int G = 0; G < 4; ++G) {
            int col = G * 256 + hu_base + n;              // gate row of W (4H x K)
            bias[G] = bih0[col] + bhh0[col];
            #pragma unroll
            for (int kt = 0; kt < 8; ++kt) {
                const float* p = Whh0 + (long)col * H_ + kt * 32 + quad * 8;
                bf16x8 v;
                #pragma unroll
                for (int j = 0; j < 8; ++j) v[j] = f2bf(p[j]);
                wf[G][kt] = v;
            }
            bf16x8 v = zero8();                           // x tile: K=16, pad to 32
            if (quad < 2) {
                const float* p = Wih0 + (long)col * NM_ + quad * 8;
                #pragma unroll
                for (int j = 0; j < 8; ++j) v[j] = f2bf(p[j]);
            }
            wf[G][8] = v;
        }
        const int  bRow = g * 16 + n;
        const long hA   = (long)bRow * S_ * H_ + quad * 8;
        f32x4 c = {0.f, 0.f, 0.f, 0.f};
        int* fl = flags0 + g * 4;
        for (int t = 0; t < S_; ++t) {
            if (threadIdx.x == 0) {
                #pragma unroll
                for (int qq = 0; qq < 4; ++qq)
                    while (__hip_atomic_load(fl + qq, __ATOMIC_ACQUIRE, __HIP_MEMORY_SCOPE_AGENT) < t)
                        __builtin_amdgcn_s_sleep(2);
            }
            __syncthreads();

            bf16x8 af[9];
            if (t > 0) {
                const short* hp = h1 + hA + (long)(t - 1) * H_;
                #pragma unroll
                for (int kt = 0; kt < 8; ++kt)
                    af[kt] = __builtin_bit_cast(bf16x8, *(const int4*)(hp + kt * 32));
            } else {
                #pragma unroll
                for (int kt = 0; kt < 8; ++kt) af[kt] = zero8();
            }
            {
                bf16x8 v = zero8();
                if (quad < 2) {
                    const float* p = x + ((long)bRow * S_ + t) * NM_ + quad * 8;
                    #pragma unroll
                    for (int j = 0; j < 8; ++j) v[j] = f2bf(p[j]);
                }
                af[8] = v;
            }
            f32x4 acc[4];
            #pragma unroll
            for (int G = 0; G < 4; ++G) {
                acc[G][0] = bias[G]; acc[G][1] = bias[G];
                acc[G][2] = bias[G]; acc[G][3] = bias[G];
            }
            #pragma unroll
            for (int kt = 0; kt < 9; ++kt)
                #pragma unroll
                for (int G = 0; G < 4; ++G)
                    acc[G] = __builtin_amdgcn_mfma_f32_16x16x32_bf16(af[kt], wf[G][kt], acc[G], 0, 0, 0);
            #pragma unroll
            for (int r = 0; r < 4; ++r) {
                float iv = sigf(acc[0][r]);
                float fv = sigf(acc[1][r]);
                float gv = tanh_(acc[2][r]);
                float ov = sigf(acc[3][r]);
                c[r] = fv * c[r] + iv * gv;
                float hv = ov * tanh_(c[r]);
                int b = g * 16 + quad * 4 + r;            // C/D: row = quad*4+reg
                h1[((long)b * S_ + t) * H_ + hu_base + n] = f2bf(hv);
            }
            __syncthreads();                               // drains vmem before barrier
            if (threadIdx.x == 0)
                __hip_atomic_store(fl + q, t + 1, __ATOMIC_RELEASE, __HIP_MEMORY_SCOPE_AGENT);
        }
    } else {
        // ---------------- layer 1 (K = 512: Whh1 | Wih1 fused) ----------------
        const int q = role - 4;
        const int hu_base = q * 64 + wv * 16;
        bf16x8 wf[4][16];
        float  bias[4];
        #pragma unroll
        for (int G = 0; G < 4; ++G) {
            int col = G * 256 + hu_base + n;
            bias[G] = bih1[col] + bhh1[col];
            #pragma unroll
            for (int kt = 0; kt < 8; ++kt) {
                const float* p = Whh1 + (long)col * H_ + kt * 32 + quad * 8;
                bf16x8 v;
                #pragma unroll
                for (int j = 0; j < 8; ++j) v[j] = f2bf(p[j]);
                wf[G][kt] = v;
            }
            #pragma unroll
            for (int kt = 0; kt < 8; ++kt) {
                const float* p = Wih1 + (long)col * H_ + kt * 32 + quad * 8;
                bf16x8 v;
                #pragma unroll
                for (int j = 0; j < 8; ++j) v[j] = f2bf(p[j]);
                wf[G][8 + kt] = v;
            }
        }
        const int  bRow = g * 16 + n;
        const long h1A  = (long)bRow * S_ * H_ + quad * 8;
        f32x4 c = {0.f, 0.f, 0.f, 0.f};
        int* fl0 = flags0 + g * 4;
        int* fl1 = flags1 + g * 4;
        for (int t = 0; t < S_; ++t) {
            if (threadIdx.x == 0) {
                #pragma unroll
                for (int qq = 0; qq < 4; ++qq) {
                    while (__hip_atomic_load(fl0 + qq, __ATOMIC_ACQUIRE, __HIP_MEMORY_SCOPE_AGENT) < t + 1)
                        __builtin_amdgcn_s_sleep(2);
                    while (__hip_atomic_load(fl1 + qq, __ATOMIC_ACQUIRE, __HIP_MEMORY_SCOPE_AGENT) < t)
                        __builtin_amdgcn_s_sleep(2);
                }
            }
            __syncthreads();

            bf16x8 af[16];
            if (t > 0) {
                const short* hp = h2ring + ((long)bRow * 2 + ((t - 1) & 1)) * H_ + quad * 8;
                #pragma unroll
                for (int kt = 0; kt < 8; ++kt)
                    af[kt] = __builtin_bit_cast(bf16x8, *(const int4*)(hp + kt * 32));
            } else {
                #pragma unroll
                for (int kt = 0; kt < 8; ++kt) af[kt] = zero8();
            }
            {
                const short* hp = h1 + h1A + (long)t * H_;
                #pragma unroll
                for (int kt = 0; kt < 8; ++kt)
                    af[8 + kt] = __builtin_bit_cast(bf16x8, *(const int4*)(hp + kt * 32));
            }
            f32x4 acc[4];
            #pragma unroll
            for (int G = 0; G < 4; ++G) {
                acc[G][0] = bias[G]; acc[G][1] = bias[G];
                acc[G][2] = bias[G]; acc[G][3] = bias[G];
            }
            #pragma unroll
            for (int kt = 0; kt < 16; ++kt)
                #pragma unroll
                for (int G = 0; G < 4; ++G)
                    acc[G] = __builtin_amdgcn_mfma_f32_16x16x32_bf16(af[kt], wf[G][kt], acc[G], 0, 0, 0);
            #pragma unroll
            for (int r = 0; r < 4; ++r) {
                float iv = sigf(acc[0][r]);
                float fv = sigf(acc[1][r]);
                float gv = tanh_(acc[2][r]);
                float ov = sigf(acc[3][r]);
                c[r] = fv * c[r] + iv * gv;
                float hv = ov * tanh_(c[r]);
                int b = g * 16 + quad * 4 + r;
                h2ring[((long)b * 2 + (t & 1)) * H_ + hu_base + n] = f2bf(hv);
                if (t == S_ - 1) hlast[b * H_ + hu_base + n] = hv;
            }
            __syncthreads();
            if (threadIdx.x == 0)
                __hip_atomic_store(fl1 + q, t + 1, __ATOMIC_RELEASE, __HIP_MEMORY_SCOPE_AGENT);
        }
    }
}

__device__ __forceinline__ float blockSum(float v, float* sbuf) {
    #pragma unroll
    for (int off = 32; off > 0; off >>= 1) v += __shfl_down(v, off, 64);
    __syncthreads();
    if ((threadIdx.x & 63) == 0) sbuf[threadIdx.x >> 6] = v;
    __syncthreads();
    return sbuf[0] + sbuf[1] + sbuf[2] + sbuf[3];
}

// LayerNorm + logits softmax + budgets softmax + beta + VIX override. One block per batch row.
__global__ __launch_bounds__(256) void tail_kernel(
    const float* __restrict__ hlast, const float* __restrict__ gamma,
    const float* __restrict__ lnbeta, const float* __restrict__ Wl,
    const float* __restrict__ bl, const float* __restrict__ rb,
    const float* __restrict__ vix, float* __restrict__ out)
{
    __shared__ float sbuf[4];
    __shared__ float pr[3], mxs[3], dens[3];
    __shared__ float bvec[32];
    const int b   = blockIdx.x;
    const int tid = threadIdx.x;

    float v  = hlast[b * H_ + tid];
    float mu = blockSum(v, sbuf) * (1.0f / 256.0f);
    float d  = v - mu;
    float var = blockSum(d * d, sbuf) * (1.0f / 256.0f);
    float hn  = d * rsqrtf(var + 1e-5f) * gamma[tid] + lnbeta[tid];

    float l[3];
    #pragma unroll
    for (int k = 0; k < 3; ++k)
        l[k] = blockSum(hn * Wl[k * H_ + tid], sbuf) + bl[k];

    if (tid == 0) {
        float m  = fmaxf(l[0], fmaxf(l[1], l[2]));
        float e0 = __expf(l[0] - m), e1 = __expf(l[1] - m), e2 = __expf(l[2] - m);
        float dn = e0 + e1 + e2;
        pr[0] = e0 / dn; pr[1] = e1 / dn; pr[2] = e2 / dn;
    }
    if (tid < 3) {
        float m = -1e30f;
        for (int p = 0; p < 32; ++p) m = fmaxf(m, rb[tid * 32 + p]);
        float dn = 0.f;
        for (int p = 0; p < 32; ++p) dn += __expf(rb[tid * 32 + p] - m);
        mxs[tid] = m; dens[tid] = dn;
    }
    __syncthreads();
    if (tid < 32) {
        float bp = 0.f;
        #pragma unroll
        for (int k = 0; k < 3; ++k)
            bp += pr[k] * __expf(rb[k * 32 + tid] - mxs[k]) / dens[k];
        bvec[tid] = bp;
    }
    __syncthreads();
    if (tid == 0) {
        bool  mask = vix[b] >= 30.0f;
        float eq_total = 0.f, cur_def = 0.f;
        for (int p = 0; p < 24; ++p) eq_total += bvec[p];
        for (int p = 24; p < 32; ++p) cur_def += bvec[p];
        float shortfall = 0.4f - cur_def;
        float ratio = fminf(shortfall / fmaxf(eq_total, 1e-8f), 0.8f);
        bool  apply = mask && (shortfall > 0.0f) && (eq_total > 1e-8f);
        float bb[32]; float ssum = 0.f;
        for (int p = 0; p < 32; ++p) {
            float b2 = (p < 24) ? bvec[p] * (1.0f - ratio) : bvec[p] + shortfall * (1.0f / 8.0f);
            float bv = apply ? b2 : bvec[p];
            bb[p] = bv; ssum += bv;
        }
        float inv = 1.0f / (ssum + 1e-8f);
        for (int p = 0; p < 32; ++p)
            out[b * 32 + p] = mask ? bb[p] * inv : bvec[p];
        #pragma unroll
        for (int k = 0; k < 3; ++k)
            out[B_ * 32 + b * 3 + k] = pr[k];
    }
}

extern "C" void kernel_launch(void* const* d_in, const int* in_sizes, int n_in,
                              void* d_out, int out_size, void* d_ws, size_t ws_size,
                              hipStream_t stream)
{
    const float* x    = (const float*)d_in[0];
    const float* vix  = (const float*)d_in[1];
    const float* Wih0 = (const float*)d_in[2];
    const float* Whh0 = (const float*)d_in[3];
    const float* bih0 = (const float*)d_in[4];
    const float* bhh0 = (const float*)d_in[5];
    const float* Wih1 = (const float*)d_in[6];
    const float* Whh1 = (const float*)d_in[7];
    const float* bih1 = (const float*)d_in[8];
    const float* bhh1 = (const float*)d_in[9];
    const float* lng  = (const float*)d_in[10];
    const float* lnb  = (const float*)d_in[11];
    const float* Wl   = (const float*)d_in[12];
    const float* bl   = (const float*)d_in[13];
    const float* rb   = (const float*)d_in[14];
    float* out = (float*)d_out;

    // ws layout (needs ~64.3 MiB):
    //   h1 history bf16 [128][1024][256]  : 67108864 B @ 0
    //   flags0/flags1 (32 ints each)      : 256 B     @ 67108864
    //   h2 ring bf16 [128][2][256]        : 131072 B  @ 67109120
    //   hlast fp32 [128][256]             : 131072 B  @ 67240192
    char*  ws     = (char*)d_ws;
    short* h1     = (short*)ws;
    int*   flags0 = (int*)(ws + 67108864);
    int*   flags1 = (int*)(ws + 67108864 + 128);
    short* h2ring = (short*)(ws + 67109120);
    float* hlast  = (float*)(ws + 67240192);

    hipMemsetAsync(ws + 67108864, 0, 256, stream);   // zero flags (ws is poisoned 0xAA)
    lstm_kernel<<<64, 256, 0, stream>>>(x, Wih0, Whh0, bih0, bhh0,
                                        Wih1, Whh1, bih1, bhh1,
                                        h1, h2ring, hlast, flags0, flags1);
    tail_kernel<<<128, 256, 0, stream>>>(hlast, lng, lnb, Wl, bl, rb, vix, out);
}

// Round 2
// 4413.476 us; speedup vs baseline: 1.7813x; 1.7813x over previous
//
#include <hip/hip_runtime.h>

#define B_  128
#define S_  1024
#define H_  256
#define NM_ 16

typedef short bf16x8 __attribute__((ext_vector_type(8)));
typedef float f32x4  __attribute__((ext_vector_type(4)));

__device__ __forceinline__ short f2bf(float f) {
    unsigned u = __builtin_bit_cast(unsigned, f);
    unsigned r = (u + 0x7FFFu + ((u >> 16) & 1u)) >> 16;   // RNE
    return (short)r;
}
__device__ __forceinline__ bf16x8 zero8() {
    bf16x8 v;
    #pragma unroll
    for (int j = 0; j < 8; ++j) v[j] = 0;
    return v;
}
__device__ __forceinline__ float sigf(float x)  { return 1.0f / (1.0f + __expf(-x)); }
__device__ __forceinline__ float tanh_(float x) { return 1.0f - 2.0f / (1.0f + __expf(2.0f * x)); }

// ---- coherent (L2-bypass, sc0 sc1) point-to-point helpers: no buffer_inv / buffer_wbl2 ----
__device__ __forceinline__ int cload_int(const int* p) {
    int r;
    asm volatile("global_load_dword %0, %1, off sc0 sc1\n\ts_waitcnt vmcnt(0)"
                 : "=v"(r) : "v"(p) : "memory");
    return r;
}
__device__ __forceinline__ void cstore_int(int* p, int v) {
    asm volatile("global_store_dword %0, %1, off sc0 sc1" :: "v"(p), "v"(v) : "memory");
}
__device__ __forceinline__ void cstore_short(short* p, int v) {
    asm volatile("global_store_short %0, %1, off sc0 sc1" :: "v"(p), "v"(v) : "memory");
}
__device__ __forceinline__ void vm_drain() {
    asm volatile("s_waitcnt vmcnt(0)" ::: "memory");
}
// 8 x 16B coherent loads (one row of h: 256 bf16, this lane reads quad*8 offsets, kt-stride 64B)
__device__ __forceinline__ void cload8x16(const short* p, bf16x8* d) {
    int4 a0, a1, a2, a3, a4, a5, a6, a7;
    asm volatile(
        "global_load_dwordx4 %0, %8, off sc0 sc1\n\t"
        "global_load_dwordx4 %1, %8, off offset:64 sc0 sc1\n\t"
        "global_load_dwordx4 %2, %8, off offset:128 sc0 sc1\n\t"
        "global_load_dwordx4 %3, %8, off offset:192 sc0 sc1\n\t"
        "global_load_dwordx4 %4, %8, off offset:256 sc0 sc1\n\t"
        "global_load_dwordx4 %5, %8, off offset:320 sc0 sc1\n\t"
        "global_load_dwordx4 %6, %8, off offset:384 sc0 sc1\n\t"
        "global_load_dwordx4 %7, %8, off offset:448 sc0 sc1\n\t"
        "s_waitcnt vmcnt(0)"
        : "=&v"(a0), "=&v"(a1), "=&v"(a2), "=&v"(a3),
          "=&v"(a4), "=&v"(a5), "=&v"(a6), "=&v"(a7)
        : "v"(p) : "memory");
    d[0] = __builtin_bit_cast(bf16x8, a0); d[1] = __builtin_bit_cast(bf16x8, a1);
    d[2] = __builtin_bit_cast(bf16x8, a2); d[3] = __builtin_bit_cast(bf16x8, a3);
    d[4] = __builtin_bit_cast(bf16x8, a4); d[5] = __builtin_bit_cast(bf16x8, a5);
    d[6] = __builtin_bit_cast(bf16x8, a6); d[7] = __builtin_bit_cast(bf16x8, a7);
}

// Fused 2-layer LSTM. Blocks 0..63: g = bx&7 (batch group, XCD-coloc), role = bx>>3.
// role 0..3  -> layer0, gate-chunk q=role      (K = 256 h0 + 16 x, 9 k-tiles)
// role 4..7  -> layer1, gate-chunk q=role-4    (K = 256 h2 + 256 h1, 16 k-tiles)
// Cross-WG h exchange entirely via sc0/sc1 (L3 point-to-point) + per-(group,role) flags.
__global__ __launch_bounds__(256, 1) void lstm_kernel(
    const float* __restrict__ x,
    const float* __restrict__ Wih0, const float* __restrict__ Whh0,
    const float* __restrict__ bih0, const float* __restrict__ bhh0,
    const float* __restrict__ Wih1, const float* __restrict__ Whh1,
    const float* __restrict__ bih1, const float* __restrict__ bhh1,
    short* __restrict__ h1, short* __restrict__ h2ring,
    float* __restrict__ hlast,
    int* __restrict__ flags0, int* __restrict__ flags1)
{
    const int g    = blockIdx.x & 7;
    const int role = blockIdx.x >> 3;
    const int lane = threadIdx.x & 63;
    const int wv   = threadIdx.x >> 6;
    const int n    = lane & 15;       // B-frag: gate col within tile; A-frag: batch row
    const int quad = lane >> 4;       // k-group / C-frag row group

    if (role < 4) {
        // ---------------- layer 0 ----------------
        const int q = role;
        const int hu_base = q * 64 + wv * 16;
        bf16x8 wf[4][9];
        float  bias[4];
        #pragma unroll
        for (int G = 0; G < 4; ++G) {
            int col = G * 256 + hu_base + n;              // gate row of W (4H x K)
            bias[G] = bih0[col] + bhh0[col];
            #pragma unroll
            for (int kt = 0; kt < 8; ++kt) {
                const float* p = Whh0 + (long)col * H_ + kt * 32 + quad * 8;
                bf16x8 v;
                #pragma unroll
                for (int j = 0; j < 8; ++j) v[j] = f2bf(p[j]);
                wf[G][kt] = v;
            }
            bf16x8 v = zero8();                           // x tile: K=16, pad to 32
            if (quad < 2) {
                const float* p = Wih0 + (long)col * NM_ + quad * 8;
                #pragma unroll
                for (int j = 0; j < 8; ++j) v[j] = f2bf(p[j]);
            }
            wf[G][8] = v;
        }
        const int  bRow = g * 16 + n;
        const long hA   = (long)bRow * S_ * H_ + quad * 8;
        f32x4 c = {0.f, 0.f, 0.f, 0.f};
        int* fl = flags0 + g * 4;
        for (int t = 0; t < S_; ++t) {
            // x tile is partner-independent: convert before the poll so it overlaps
            bf16x8 xfrag = zero8();
            if (quad < 2) {
                const float* p = x + ((long)bRow * S_ + t) * NM_ + quad * 8;
                #pragma unroll
                for (int j = 0; j < 8; ++j) xfrag[j] = f2bf(p[j]);
            }
            // parallel poll: thread tid<4 polls flag tid >= t (relaxed sc loads, no inv)
            if (threadIdx.x < 4) {
                while (cload_int(fl + threadIdx.x) < t) __builtin_amdgcn_s_sleep(1);
            }
            __syncthreads();

            bf16x8 af[9];
            if (t > 0) {
                cload8x16(h1 + hA + (long)(t - 1) * H_, af);
            } else {
                #pragma unroll
                for (int kt = 0; kt < 8; ++kt) af[kt] = zero8();
            }
            af[8] = xfrag;

            f32x4 acc[4];
            #pragma unroll
            for (int G = 0; G < 4; ++G) {
                acc[G][0] = bias[G]; acc[G][1] = bias[G];
                acc[G][2] = bias[G]; acc[G][3] = bias[G];
            }
            #pragma unroll
            for (int kt = 0; kt < 9; ++kt)
                #pragma unroll
                for (int G = 0; G < 4; ++G)
                    acc[G] = __builtin_amdgcn_mfma_f32_16x16x32_bf16(af[kt], wf[G][kt], acc[G], 0, 0, 0);
            #pragma unroll
            for (int r = 0; r < 4; ++r) {
                float iv = sigf(acc[0][r]);
                float fv = sigf(acc[1][r]);
                float gv = tanh_(acc[2][r]);
                float ov = sigf(acc[3][r]);
                c[r] = fv * c[r] + iv * gv;
                float hv = ov * tanh_(c[r]);
                int b = g * 16 + quad * 4 + r;            // C/D: row = quad*4+reg
                cstore_short(h1 + ((long)b * S_ + t) * H_ + hu_base + n, (int)(unsigned short)f2bf(hv));
            }
            vm_drain();                                    // this thread's sc stores visible at L3
            __syncthreads();                               // all threads' stores drained
            if (threadIdx.x == 0) cstore_int(fl + q, t + 1);
        }
    } else {
        // ---------------- layer 1 (K = 512: Whh1 | Wih1 fused) ----------------
        const int q = role - 4;
        const int hu_base = q * 64 + wv * 16;
        bf16x8 wf[4][16];
        float  bias[4];
        #pragma unroll
        for (int G = 0; G < 4; ++G) {
            int col = G * 256 + hu_base + n;
            bias[G] = bih1[col] + bhh1[col];
            #pragma unroll
            for (int kt = 0; kt < 8; ++kt) {
                const float* p = Whh1 + (long)col * H_ + kt * 32 + quad * 8;
                bf16x8 v;
                #pragma unroll
                for (int j = 0; j < 8; ++j) v[j] = f2bf(p[j]);
                wf[G][kt] = v;
            }
            #pragma unroll
            for (int kt = 0; kt < 8; ++kt) {
                const float* p = Wih1 + (long)col * H_ + kt * 32 + quad * 8;
                bf16x8 v;
                #pragma unroll
                for (int j = 0; j < 8; ++j) v[j] = f2bf(p[j]);
                wf[G][8 + kt] = v;
            }
        }
        const int  bRow = g * 16 + n;
        const long h1A  = (long)bRow * S_ * H_ + quad * 8;
        f32x4 c = {0.f, 0.f, 0.f, 0.f};
        int* fl0 = flags0 + g * 4;
        int* fl1 = flags1 + g * 4;
        for (int t = 0; t < S_; ++t) {
            // parallel poll: tid<4 -> fl0[tid] >= t+1 (h1(t) ready); tid 4..7 -> fl1 >= t
            if (threadIdx.x < 8) {
                const int* fp = (threadIdx.x < 4) ? (fl0 + threadIdx.x) : (fl1 + threadIdx.x - 4);
                const int  tgt = (threadIdx.x < 4) ? (t + 1) : t;
                while (cload_int(fp) < tgt) __builtin_amdgcn_s_sleep(1);
            }
            __syncthreads();

            bf16x8 af[16];
            if (t > 0) {
                cload8x16(h2ring + ((long)bRow * 2 + ((t - 1) & 1)) * H_ + quad * 8, af);
            } else {
                #pragma unroll
                for (int kt = 0; kt < 8; ++kt) af[kt] = zero8();
            }
            cload8x16(h1 + h1A + (long)t * H_, af + 8);

            f32x4 acc[4];
            #pragma unroll
            for (int G = 0; G < 4; ++G) {
                acc[G][0] = bias[G]; acc[G][1] = bias[G];
                acc[G][2] = bias[G]; acc[G][3] = bias[G];
            }
            #pragma unroll
            for (int kt = 0; kt < 16; ++kt)
                #pragma unroll
                for (int G = 0; G < 4; ++G)
                    acc[G] = __builtin_amdgcn_mfma_f32_16x16x32_bf16(af[kt], wf[G][kt], acc[G], 0, 0, 0);
            #pragma unroll
            for (int r = 0; r < 4; ++r) {
                float iv = sigf(acc[0][r]);
                float fv = sigf(acc[1][r]);
                float gv = tanh_(acc[2][r]);
                float ov = sigf(acc[3][r]);
                c[r] = fv * c[r] + iv * gv;
                float hv = ov * tanh_(c[r]);
                int b = g * 16 + quad * 4 + r;
                cstore_short(h2ring + ((long)b * 2 + (t & 1)) * H_ + hu_base + n,
                             (int)(unsigned short)f2bf(hv));
                if (t == S_ - 1) hlast[b * H_ + hu_base + n] = hv;   // normal store: read next dispatch
            }
            vm_drain();
            __syncthreads();
            if (threadIdx.x == 0) cstore_int(fl1 + q, t + 1);
        }
    }
}

__device__ __forceinline__ float blockSum(float v, float* sbuf) {
    #pragma unroll
    for (int off = 32; off > 0; off >>= 1) v += __shfl_down(v, off, 64);
    __syncthreads();
    if ((threadIdx.x & 63) == 0) sbuf[threadIdx.x >> 6] = v;
    __syncthreads();
    return sbuf[0] + sbuf[1] + sbuf[2] + sbuf[3];
}

// LayerNorm + logits softmax + budgets softmax + beta + VIX override. One block per batch row.
__global__ __launch_bounds__(256) void tail_kernel(
    const float* __restrict__ hlast, const float* __restrict__ gamma,
    const float* __restrict__ lnbeta, const float* __restrict__ Wl,
    const float* __restrict__ bl, const float* __restrict__ rb,
    const float* __restrict__ vix, float* __restrict__ out)
{
    __shared__ float sbuf[4];
    __shared__ float pr[3], mxs[3], dens[3];
    __shared__ float bvec[32];
    const int b   = blockIdx.x;
    const int tid = threadIdx.x;

    float v  = hlast[b * H_ + tid];
    float mu = blockSum(v, sbuf) * (1.0f / 256.0f);
    float d  = v - mu;
    float var = blockSum(d * d, sbuf) * (1.0f / 256.0f);
    float hn  = d * rsqrtf(var + 1e-5f) * gamma[tid] + lnbeta[tid];

    float l[3];
    #pragma unroll
    for (int k = 0; k < 3; ++k)
        l[k] = blockSum(hn * Wl[k * H_ + tid], sbuf) + bl[k];

    if (tid == 0) {
        float m  = fmaxf(l[0], fmaxf(l[1], l[2]));
        float e0 = __expf(l[0] - m), e1 = __expf(l[1] - m), e2 = __expf(l[2] - m);
        float dn = e0 + e1 + e2;
        pr[0] = e0 / dn; pr[1] = e1 / dn; pr[2] = e2 / dn;
    }
    if (tid < 3) {
        float m = -1e30f;
        for (int p = 0; p < 32; ++p) m = fmaxf(m, rb[tid * 32 + p]);
        float dn = 0.f;
        for (int p = 0; p < 32; ++p) dn += __expf(rb[tid * 32 + p] - m);
        mxs[tid] = m; dens[tid] = dn;
    }
    __syncthreads();
    if (tid < 32) {
        float bp = 0.f;
        #pragma unroll
        for (int k = 0; k < 3; ++k)
            bp += pr[k] * __expf(rb[k * 32 + tid] - mxs[k]) / dens[k];
        bvec[tid] = bp;
    }
    __syncthreads();
    if (tid == 0) {
        bool  mask = vix[b] >= 30.0f;
        float eq_total = 0.f, cur_def = 0.f;
        for (int p = 0; p < 24; ++p) eq_total += bvec[p];
        for (int p = 24; p < 32; ++p) cur_def += bvec[p];
        float shortfall = 0.4f - cur_def;
        float ratio = fminf(shortfall / fmaxf(eq_total, 1e-8f), 0.8f);
        bool  apply = mask && (shortfall > 0.0f) && (eq_total > 1e-8f);
        float bb[32]; float ssum = 0.f;
        for (int p = 0; p < 32; ++p) {
            float b2 = (p < 24) ? bvec[p] * (1.0f - ratio) : bvec[p] + shortfall * (1.0f / 8.0f);
            float bv = apply ? b2 : bvec[p];
            bb[p] = bv; ssum += bv;
        }
        float inv = 1.0f / (ssum + 1e-8f);
        for (int p = 0; p < 32; ++p)
            out[b * 32 + p] = mask ? bb[p] * inv : bvec[p];
        #pragma unroll
        for (int k = 0; k < 3; ++k)
            out[B_ * 32 + b * 3 + k] = pr[k];
    }
}

extern "C" void kernel_launch(void* const* d_in, const int* in_sizes, int n_in,
                              void* d_out, int out_size, void* d_ws, size_t ws_size,
                              hipStream_t stream)
{
    const float* x    = (const float*)d_in[0];
    const float* vix  = (const float*)d_in[1];
    const float* Wih0 = (const float*)d_in[2];
    const float* Whh0 = (const float*)d_in[3];
    const float* bih0 = (const float*)d_in[4];
    const float* bhh0 = (const float*)d_in[5];
    const float* Wih1 = (const float*)d_in[6];
    const float* Whh1 = (const float*)d_in[7];
    const float* bih1 = (const float*)d_in[8];
    const float* bhh1 = (const float*)d_in[9];
    const float* lng  = (const float*)d_in[10];
    const float* lnb  = (const float*)d_in[11];
    const float* Wl   = (const float*)d_in[12];
    const float* bl   = (const float*)d_in[13];
    const float* rb   = (const float*)d_in[14];
    float* out = (float*)d_out;

    // ws layout (needs ~64.3 MiB):
    //   h1 history bf16 [128][1024][256]  : 67108864 B @ 0
    //   flags0/flags1 (32 ints each)      : 256 B     @ 67108864
    //   h2 ring bf16 [128][2][256]        : 131072 B  @ 67109120
    //   hlast fp32 [128][256]             : 131072 B  @ 67240192
    char*  ws     = (char*)d_ws;
    short* h1     = (short*)ws;
    int*   flags0 = (int*)(ws + 67108864);
    int*   flags1 = (int*)(ws + 67108864 + 128);
    short* h2ring = (short*)(ws + 67109120);
    float* hlast  = (float*)(ws + 67240192);

    hipMemsetAsync(ws + 67108864, 0, 256, stream);   // zero flags (ws is poisoned 0xAA)
    lstm_kernel<<<64, 256, 0, stream>>>(x, Wih0, Whh0, bih0, bhh0,
                                        Wih1, Whh1, bih1, bhh1,
                                        h1, h2ring, hlast, flags0, flags1);
    tail_kernel<<<128, 256, 0, stream>>>(hlast, lng, lnb, Wl, bl, rb, vix, out);
}

// Round 5
// 4123.816 us; speedup vs baseline: 1.9064x; 1.0702x over previous
//
#include <hip/hip_runtime.h>

#define B_  128
#define S_  1024
#define H_  256
#define NM_ 16

typedef short bf16x8 __attribute__((ext_vector_type(8)));
typedef float f32x4  __attribute__((ext_vector_type(4)));

__device__ __forceinline__ short f2bf(float f) {
    unsigned u = __builtin_bit_cast(unsigned, f);
    unsigned r = (u + 0x7FFFu + ((u >> 16) & 1u)) >> 16;   // RNE
    return (short)r;
}
__device__ __forceinline__ bf16x8 zero8() {
    bf16x8 v;
    #pragma unroll
    for (int j = 0; j < 8; ++j) v[j] = 0;
    return v;
}
__device__ __forceinline__ float sigf(float x)  { return 1.0f / (1.0f + __expf(-x)); }
__device__ __forceinline__ float tanh_(float x) { return 1.0f - 2.0f / (1.0f + __expf(2.0f * x)); }
__device__ __forceinline__ void vm_drain() {
    asm volatile("s_waitcnt vmcnt(0)" ::: "memory");
}

// ---- coherent (L2-bypass, sc0 sc1) point-to-point helpers: no buffer_inv / buffer_wbl2 ----
// (exact round-2-proven protocol; flags are padded to one 128B line each to kill
//  the single-line contention all 16 writers + 64 pollers previously shared)
__device__ __forceinline__ int cload_int(const int* p) {
    int r;
    asm volatile("global_load_dword %0, %1, off sc0 sc1\n\ts_waitcnt vmcnt(0)"
                 : "=v"(r) : "v"(p) : "memory");
    return r;
}
__device__ __forceinline__ void cstore_int(int* p, int v) {
    asm volatile("global_store_dword %0, %1, off sc0 sc1" :: "v"(p), "v"(v) : "memory");
}
__device__ __forceinline__ void cstore_short(short* p, int v) {
    asm volatile("global_store_short %0, %1, off sc0 sc1" :: "v"(p), "v"(v) : "memory");
}
// 8 x 16B coherent loads (one 256-bf16 h row; lane offset quad*8, kt-stride 64B)
__device__ __forceinline__ void cload8x16(const short* p, bf16x8* d) {
    int4 a0, a1, a2, a3, a4, a5, a6, a7;
    asm volatile(
        "global_load_dwordx4 %0, %8, off sc0 sc1\n\t"
        "global_load_dwordx4 %1, %8, off offset:64 sc0 sc1\n\t"
        "global_load_dwordx4 %2, %8, off offset:128 sc0 sc1\n\t"
        "global_load_dwordx4 %3, %8, off offset:192 sc0 sc1\n\t"
        "global_load_dwordx4 %4, %8, off offset:256 sc0 sc1\n\t"
        "global_load_dwordx4 %5, %8, off offset:320 sc0 sc1\n\t"
        "global_load_dwordx4 %6, %8, off offset:384 sc0 sc1\n\t"
        "global_load_dwordx4 %7, %8, off offset:448 sc0 sc1\n\t"
        "s_waitcnt vmcnt(0)"
        : "=&v"(a0), "=&v"(a1), "=&v"(a2), "=&v"(a3),
          "=&v"(a4), "=&v"(a5), "=&v"(a6), "=&v"(a7)
        : "v"(p) : "memory");
    d[0] = __builtin_bit_cast(bf16x8, a0); d[1] = __builtin_bit_cast(bf16x8, a1);
    d[2] = __builtin_bit_cast(bf16x8, a2); d[3] = __builtin_bit_cast(bf16x8, a3);
    d[4] = __builtin_bit_cast(bf16x8, a4); d[5] = __builtin_bit_cast(bf16x8, a5);
    d[6] = __builtin_bit_cast(bf16x8, a6); d[7] = __builtin_bit_cast(bf16x8, a7);
}

// Fused 2-layer LSTM. Blocks 0..63: g = bx&7 (batch group), role = bx>>3.
// role 0..3  -> layer0, gate-chunk q=role      (K = 256 h0 + 16 x, 9 k-tiles)
// role 4..7  -> layer1, gate-chunk q=role-4    (K = 256 h2 + 256 h1, 16 k-tiles)
// h1 is a 4-deep L3-resident ring; back-pressure: L0(t) additionally needs fl1 >= t-3
// (slot t&3 held h1(t-4), consumed once L1 completed step t-4 -> fl1 = t-3).
// Flags are padded: flag f lives at base + f*128B (32 ints apart).
__global__ __launch_bounds__(256, 1) void lstm_kernel(
    const float* __restrict__ x,
    const float* __restrict__ Wih0, const float* __restrict__ Whh0,
    const float* __restrict__ bih0, const float* __restrict__ bhh0,
    const float* __restrict__ Wih1, const float* __restrict__ Whh1,
    const float* __restrict__ bih1, const float* __restrict__ bhh1,
    short* __restrict__ h1ring, short* __restrict__ h2ring,
    float* __restrict__ hlast,
    int* __restrict__ flags0, int* __restrict__ flags1)
{
    const int g    = blockIdx.x & 7;
    const int role = blockIdx.x >> 3;
    const int lane = threadIdx.x & 63;
    const int wv   = threadIdx.x >> 6;
    const int n    = lane & 15;       // B-frag: gate col within tile; A-frag: batch row
    const int quad = lane >> 4;       // k-group / C-frag row group

    int* fl0 = flags0 + (g * 4) * 32; // this group's 4 layer-0 flags, 128B apart
    int* fl1 = flags1 + (g * 4) * 32;

    if (role < 4) {
        // ---------------- layer 0 ----------------
        const int q = role;
        const int hu_base = q * 64 + wv * 16;
        bf16x8 wf[4][9];
        float  bias[4];
        #pragma unroll
        for (int G = 0; G < 4; ++G) {
            int col = G * 256 + hu_base + n;              // gate row of W (4H x K)
            bias[G] = bih0[col] + bhh0[col];
            #pragma unroll
            for (int kt = 0; kt < 8; ++kt) {
                const float* p = Whh0 + (long)col * H_ + kt * 32 + quad * 8;
                bf16x8 v;
                #pragma unroll
                for (int j = 0; j < 8; ++j) v[j] = f2bf(p[j]);
                wf[G][kt] = v;
            }
            bf16x8 v = zero8();                           // x tile: K=16, pad to 32
            if (quad < 2) {
                const float* p = Wih0 + (long)col * NM_ + quad * 8;
                #pragma unroll
                for (int j = 0; j < 8; ++j) v[j] = f2bf(p[j]);
            }
            wf[G][8] = v;
        }
        const int bRow = g * 16 + n;
        f32x4 c = {0.f, 0.f, 0.f, 0.f};
        for (int t = 0; t < S_; ++t) {
            bf16x8 xfrag = zero8();                       // partner-independent: overlap with poll
            if (quad < 2) {
                const float* p = x + ((long)bRow * S_ + t) * NM_ + quad * 8;
                #pragma unroll
                for (int j = 0; j < 8; ++j) xfrag[j] = f2bf(p[j]);
            }
            // tid<4: peers fl0 >= t (h1(t-1) ready); tid 4..7: fl1 >= t-3 (ring slot free)
            if (threadIdx.x < 8) {
                const int* fp  = (threadIdx.x < 4) ? (fl0 + threadIdx.x * 32)
                                                   : (fl1 + (threadIdx.x - 4) * 32);
                const int  tgt = (threadIdx.x < 4) ? t : (t - 3);
                while (cload_int(fp) < tgt) __builtin_amdgcn_s_sleep(1);
            }
            __syncthreads();

            bf16x8 af[9];
            if (t > 0) {
                cload8x16(h1ring + (((long)((t - 1) & 3) * B_ + bRow) * H_) + quad * 8, af);
            } else {
                #pragma unroll
                for (int kt = 0; kt < 8; ++kt) af[kt] = zero8();
            }
            af[8] = xfrag;

            f32x4 acc[4];
            #pragma unroll
            for (int G = 0; G < 4; ++G) {
                acc[G][0] = bias[G]; acc[G][1] = bias[G];
                acc[G][2] = bias[G]; acc[G][3] = bias[G];
            }
            #pragma unroll
            for (int kt = 0; kt < 9; ++kt)
                #pragma unroll
                for (int G = 0; G < 4; ++G)
                    acc[G] = __builtin_amdgcn_mfma_f32_16x16x32_bf16(af[kt], wf[G][kt], acc[G], 0, 0, 0);
            #pragma unroll
            for (int r = 0; r < 4; ++r) {
                float iv = sigf(acc[0][r]);
                float fv = sigf(acc[1][r]);
                float gv = tanh_(acc[2][r]);
                float ov = sigf(acc[3][r]);
                c[r] = fv * c[r] + iv * gv;
                float hv = ov * tanh_(c[r]);
                int b = g * 16 + quad * 4 + r;            // C/D: row = quad*4+reg
                cstore_short(h1ring + (((long)(t & 3) * B_ + b) * H_) + hu_base + n,
                             (int)(unsigned short)f2bf(hv));
            }
            vm_drain();                                    // this thread's stores visible at L3
            __syncthreads();                               // all threads' stores drained
            if (threadIdx.x == 0) cstore_int(fl0 + q * 32, t + 1);
        }
    } else {
        // ---------------- layer 1 (K = 512: Whh1 | Wih1 fused) ----------------
        const int q = role - 4;
        const int hu_base = q * 64 + wv * 16;
        bf16x8 wf[4][16];
        float  bias[4];
        #pragma unroll
        for (int G = 0; G < 4; ++G) {
            int col = G * 256 + hu_base + n;
            bias[G] = bih1[col] + bhh1[col];
            #pragma unroll
            for (int kt = 0; kt < 8; ++kt) {
                const float* p = Whh1 + (long)col * H_ + kt * 32 + quad * 8;
                bf16x8 v;
                #pragma unroll
                for (int j = 0; j < 8; ++j) v[j] = f2bf(p[j]);
                wf[G][kt] = v;
            }
            #pragma unroll
            for (int kt = 0; kt < 8; ++kt) {
                const float* p = Wih1 + (long)col * H_ + kt * 32 + quad * 8;
                bf16x8 v;
                #pragma unroll
                for (int j = 0; j < 8; ++j) v[j] = f2bf(p[j]);
                wf[G][8 + kt] = v;
            }
        }
        const int bRow = g * 16 + n;
        f32x4 c = {0.f, 0.f, 0.f, 0.f};
        for (int t = 0; t < S_; ++t) {
            // tid<4 -> fl0 >= t+1 (h1(t) ready); tid 4..7 -> fl1 >= t (h2(t-1) ready)
            if (threadIdx.x < 8) {
                const int* fp  = (threadIdx.x < 4) ? (fl0 + threadIdx.x * 32)
                                                   : (fl1 + (threadIdx.x - 4) * 32);
                const int  tgt = (threadIdx.x < 4) ? (t + 1) : t;
                while (cload_int(fp) < tgt) __builtin_amdgcn_s_sleep(1);
            }
            __syncthreads();

            bf16x8 af[16];
            if (t > 0) {
                cload8x16(h2ring + ((long)bRow * 2 + ((t - 1) & 1)) * H_ + quad * 8, af);
            } else {
                #pragma unroll
                for (int kt = 0; kt < 8; ++kt) af[kt] = zero8();
            }
            cload8x16(h1ring + (((long)(t & 3) * B_ + bRow) * H_) + quad * 8, af + 8);

            f32x4 acc[4];
            #pragma unroll
            for (int G = 0; G < 4; ++G) {
                acc[G][0] = bias[G]; acc[G][1] = bias[G];
                acc[G][2] = bias[G]; acc[G][3] = bias[G];
            }
            #pragma unroll
            for (int kt = 0; kt < 16; ++kt)
                #pragma unroll
                for (int G = 0; G < 4; ++G)
                    acc[G] = __builtin_amdgcn_mfma_f32_16x16x32_bf16(af[kt], wf[G][kt], acc[G], 0, 0, 0);
            #pragma unroll
            for (int r = 0; r < 4; ++r) {
                float iv = sigf(acc[0][r]);
                float fv = sigf(acc[1][r]);
                float gv = tanh_(acc[2][r]);
                float ov = sigf(acc[3][r]);
                c[r] = fv * c[r] + iv * gv;
                float hv = ov * tanh_(c[r]);
                int b = g * 16 + quad * 4 + r;
                cstore_short(h2ring + ((long)b * 2 + (t & 1)) * H_ + hu_base + n,
                             (int)(unsigned short)f2bf(hv));
                if (t == S_ - 1) hlast[b * H_ + hu_base + n] = hv;   // read next dispatch
            }
            vm_drain();
            __syncthreads();
            if (threadIdx.x == 0) cstore_int(fl1 + q * 32, t + 1);
        }
    }
}

__device__ __forceinline__ float blockSum(float v, float* sbuf) {
    #pragma unroll
    for (int off = 32; off > 0; off >>= 1) v += __shfl_down(v, off, 64);
    __syncthreads();
    if ((threadIdx.x & 63) == 0) sbuf[threadIdx.x >> 6] = v;
    __syncthreads();
    return sbuf[0] + sbuf[1] + sbuf[2] + sbuf[3];
}

// LayerNorm + logits softmax + budgets softmax + beta + VIX override. One block per batch row.
__global__ __launch_bounds__(256) void tail_kernel(
    const float* __restrict__ hlast, const float* __restrict__ gamma,
    const float* __restrict__ lnbeta, const float* __restrict__ Wl,
    const float* __restrict__ bl, const float* __restrict__ rb,
    const float* __restrict__ vix, float* __restrict__ out)
{
    __shared__ float sbuf[4];
    __shared__ float pr[3], mxs[3], dens[3];
    __shared__ float bvec[32];
    const int b   = blockIdx.x;
    const int tid = threadIdx.x;

    float v  = hlast[b * H_ + tid];
    float mu = blockSum(v, sbuf) * (1.0f / 256.0f);
    float d  = v - mu;
    float var = blockSum(d * d, sbuf) * (1.0f / 256.0f);
    float hn  = d * rsqrtf(var + 1e-5f) * gamma[tid] + lnbeta[tid];

    float l[3];
    #pragma unroll
    for (int k = 0; k < 3; ++k)
        l[k] = blockSum(hn * Wl[k * H_ + tid], sbuf) + bl[k];

    if (tid == 0) {
        float m  = fmaxf(l[0], fmaxf(l[1], l[2]));
        float e0 = __expf(l[0] - m), e1 = __expf(l[1] - m), e2 = __expf(l[2] - m);
        float dn = e0 + e1 + e2;
        pr[0] = e0 / dn; pr[1] = e1 / dn; pr[2] = e2 / dn;
    }
    if (tid < 3) {
        float m = -1e30f;
        for (int p = 0; p < 32; ++p) m = fmaxf(m, rb[tid * 32 + p]);
        float dn = 0.f;
        for (int p = 0; p < 32; ++p) dn += __expf(rb[tid * 32 + p] - m);
        mxs[tid] = m; dens[tid] = dn;
    }
    __syncthreads();
    if (tid < 32) {
        float bp = 0.f;
        #pragma unroll
        for (int k = 0; k < 3; ++k)
            bp += pr[k] * __expf(rb[k * 32 + tid] - mxs[k]) / dens[k];
        bvec[tid] = bp;
    }
    __syncthreads();
    if (tid == 0) {
        bool  mask = vix[b] >= 30.0f;
        float eq_total = 0.f, cur_def = 0.f;
        for (int p = 0; p < 24; ++p) eq_total += bvec[p];
        for (int p = 24; p < 32; ++p) cur_def += bvec[p];
        float shortfall = 0.4f - cur_def;
        float ratio = fminf(shortfall / fmaxf(eq_total, 1e-8f), 0.8f);
        bool  apply = mask && (shortfall > 0.0f) && (eq_total > 1e-8f);
        float bb[32]; float ssum = 0.f;
        for (int p = 0; p < 32; ++p) {
            float b2 = (p < 24) ? bvec[p] * (1.0f - ratio) : bvec[p] + shortfall * (1.0f / 8.0f);
            float bv = apply ? b2 : bvec[p];
            bb[p] = bv; ssum += bv;
        }
        float inv = 1.0f / (ssum + 1e-8f);
        for (int p = 0; p < 32; ++p)
            out[b * 32 + p] = mask ? bb[p] * inv : bvec[p];
        #pragma unroll
        for (int k = 0; k < 3; ++k)
            out[B_ * 32 + b * 3 + k] = pr[k];
    }
}

extern "C" void kernel_launch(void* const* d_in, const int* in_sizes, int n_in,
                              void* d_out, int out_size, void* d_ws, size_t ws_size,
                              hipStream_t stream)
{
    const float* x    = (const float*)d_in[0];
    const float* vix  = (const float*)d_in[1];
    const float* Wih0 = (const float*)d_in[2];
    const float* Whh0 = (const float*)d_in[3];
    const float* bih0 = (const float*)d_in[4];
    const float* bhh0 = (const float*)d_in[5];
    const float* Wih1 = (const float*)d_in[6];
    const float* Whh1 = (const float*)d_in[7];
    const float* bih1 = (const float*)d_in[8];
    const float* bhh1 = (const float*)d_in[9];
    const float* lng  = (const float*)d_in[10];
    const float* lnb  = (const float*)d_in[11];
    const float* Wl   = (const float*)d_in[12];
    const float* bl   = (const float*)d_in[13];
    const float* rb   = (const float*)d_in[14];
    float* out = (float*)d_out;

    // ws layout (~520 KB):
    //   h1ring bf16 [4][128][256]   : 262144 B @ 0
    //   h2ring bf16 [128][2][256]   : 131072 B @ 262144
    //   hlast  fp32 [128][256]      : 131072 B @ 393216
    //   flags0: 32 flags x 128B     : 4096 B   @ 524288   (memset 0)
    //   flags1: 32 flags x 128B     : 4096 B   @ 528384   (memset 0)
    char*  ws     = (char*)d_ws;
    short* h1ring = (short*)ws;
    short* h2ring = (short*)(ws + 262144);
    float* hlast  = (float*)(ws + 393216);
    int*   flags0 = (int*)(ws + 524288);
    int*   flags1 = (int*)(ws + 528384);

    hipMemsetAsync(ws + 524288, 0, 8192, stream);   // zero padded flags (ws is poisoned 0xAA)
    lstm_kernel<<<64, 256, 0, stream>>>(x, Wih0, Whh0, bih0, bhh0,
                                        Wih1, Whh1, bih1, bhh1,
                                        h1ring, h2ring, hlast, flags0, flags1);
    tail_kernel<<<128, 256, 0, stream>>>(hlast, lng, lnb, Wl, bl, rb, vix, out);
}